// Round 6
// baseline (636.599 us; speedup 1.0000x reference)
//
#include <hip/hip_runtime.h>
#include <hip/hip_bf16.h>
#include <hip/hip_fp16.h>
#include <math.h>

#define DMODEL 128
#define NHEAD 8
#define HEADD 16
#define NLAYER 2
#define FFDIM 512
#define MPAD 50048      // N rounded up to 128 (782 tiles of 64)
#define QKVW 384        // fused qkv row width in ushorts: [q 0..127 | kv interleaved 128..383]

using short8 = __attribute__((ext_vector_type(8))) short;
using half8  = __attribute__((ext_vector_type(8))) _Float16;
using f32x4  = __attribute__((ext_vector_type(4))) float;

static __device__ __forceinline__ unsigned short f2h(float f) {
    __half h = __float2half(f);               // RNE
    unsigned short u; __builtin_memcpy(&u, &h, 2); return u;
}
static __device__ __forceinline__ float h2f(unsigned short u) {
    __half h; __builtin_memcpy(&h, &u, 2); return __half2float(h);
}
static __device__ __forceinline__ half8 s2h8(short8 s) {
    half8 h; __builtin_memcpy(&h, &s, 16); return h;
}
static __device__ __forceinline__ f32x4 MFMAH(short8 a, short8 b, f32x4 c) {
    return __builtin_amdgcn_mfma_f32_16x16x32_f16(s2h8(a), s2h8(b), c, 0, 0, 0);
}
// gelu via exp-based tanh; max |delta| vs erf-gelu ~3e-4 (margin is 0.29).
static __device__ __forceinline__ float gelu_fast(float v) {
    float u = v * (0.7978845608f + 0.0356774081f * v * v);
    float t = 1.0f - 2.0f / (1.0f + __expf(2.0f * u));
    return 0.5f * v * (1.0f + t);
}

// ---------------------------------------------------------------------------
// LayerNorm standalone (only used once: layer-0 LN1 from the initial x copy).
// ---------------------------------------------------------------------------
__global__ __launch_bounds__(256)
void ln_kernel(const float* __restrict__ x, const float* __restrict__ g,
               const float* __restrict__ b, unsigned short* __restrict__ out, int n)
{
    int wave = threadIdx.x >> 6;
    int lane = threadIdx.x & 63;
    int row  = blockIdx.x * 4 + wave;
    if (row >= n) return;
    float2 xv = *(const float2*)(x + (size_t)row * DMODEL + lane * 2);
    float s  = xv.x + xv.y;
    float ss = xv.x * xv.x + xv.y * xv.y;
    #pragma unroll
    for (int d = 1; d < 64; d <<= 1) {
        s  += __shfl_xor(s, d);
        ss += __shfl_xor(ss, d);
    }
    float mu   = s * (1.0f / 128.0f);
    float var  = ss * (1.0f / 128.0f) - mu * mu;
    float rstd = rsqrtf(var + 1e-5f);
    float2 gv = *(const float2*)(g + lane * 2);
    float2 bv = *(const float2*)(b + lane * 2);
    ushort2 o;
    o.x = f2h((xv.x - mu) * rstd * gv.x + bv.x);
    o.y = f2h((xv.y - mu) * rstd * gv.y + bv.y);
    *(ushort2*)(out + (size_t)row * DMODEL + lane * 2) = o;
}

// ---------------------------------------------------------------------------
// All weight conversions in ONE launch (fp32 [K][N] -> fp16 [N][K] layouts).
// ---------------------------------------------------------------------------
__global__ void wconv_all(const float* __restrict__ Wq, const float* __restrict__ Wk,
                          const float* __restrict__ Wv, const float* __restrict__ Wo,
                          const float* __restrict__ Wpos, const float* __restrict__ W1,
                          const float* __restrict__ W2,
                          unsigned short* __restrict__ wqkvt, unsigned short* __restrict__ wot,
                          unsigned short* __restrict__ wpt, unsigned short* __restrict__ w1t,
                          unsigned short* __restrict__ w2t)
{
    const int DD = NLAYER * DMODEL * DMODEL;   // 32768
    const int DF = NLAYER * DMODEL * FFDIM;    // 131072
    int i = blockIdx.x * 256 + threadIdx.x;
    if (i < 3 * DD) {                          // Wq/Wk/Wv -> wqkvt [2][384][128]
        int w = i / DD, r = i - w * DD;
        const float* src = (w == 0) ? Wq : (w == 1 ? Wk : Wv);
        int l = r >> 14, rr = r & 16383;
        int k = rr >> 7, nn = rr & 127;
        wqkvt[(size_t)l * QKVW * DMODEL + (size_t)(w * 128 + nn) * DMODEL + k] = f2h(src[r]);
    } else if (i < 5 * DD) {                   // Wo/Wpos -> [2][128][128]
        int w = (i - 3 * DD) / DD, r = (i - 3 * DD) - w * DD;
        const float* src = (w == 0) ? Wo : Wpos;
        unsigned short* dst = (w == 0) ? wot : wpt;
        int l = r >> 14, rr = r & 16383;
        int k = rr >> 7, nn = rr & 127;
        dst[(size_t)l * DMODEL * DMODEL + (size_t)nn * DMODEL + k] = f2h(src[r]);
    } else if (i < 5 * DD + DF) {              // W1 [2][128][512] -> w1t [2][512][128]
        int r = i - 5 * DD;
        int l = r >> 16, rr = r & 65535;
        int k = rr >> 9, nn = rr & 511;
        w1t[(size_t)l * FFDIM * DMODEL + (size_t)nn * DMODEL + k] = f2h(W1[r]);
    } else if (i < 5 * DD + 2 * DF) {          // W2 [2][512][128] -> w2t [2][128][512]
        int r = i - 5 * DD - DF;
        int l = r >> 16, rr = r & 65535;
        int k = rr >> 7, nn = rr & 127;
        w2t[(size_t)l * DMODEL * FFDIM + (size_t)nn * FFDIM + k] = f2h(W2[r]);
    }
}

// init: deg=1 (self loop), counts=0, cursor=0, stats=0
__global__ void init_all(float* __restrict__ deg, int* __restrict__ counts,
                         int* __restrict__ cursor, float* __restrict__ stats, int n)
{
    int i = blockIdx.x * 256 + threadIdx.x;
    if (i < n) { deg[i] = 1.0f; counts[i] = 0; cursor[i] = 0; }
    if (i == 0) stats[0] = 0.f;
}

__global__ void deg_count(const int* __restrict__ src, float* __restrict__ deg, int e)
{
    int i = blockIdx.x * 256 + threadIdx.x;
    if (i < e) atomicAdd(&deg[src[i]], 1.0f);
}

__global__ __launch_bounds__(256)
void deg_var(const float* __restrict__ deg, float* __restrict__ stats, float mean, int n)
{
    float acc = 0.f;
    for (int i = blockIdx.x * blockDim.x + threadIdx.x; i < n; i += gridDim.x * blockDim.x) {
        float d = deg[i] - mean;
        acc += d * d;
    }
    #pragma unroll
    for (int d = 1; d < 64; d <<= 1) acc += __shfl_xor(acc, d);
    __shared__ float wsum[4];
    int lane = threadIdx.x & 63, wv = threadIdx.x >> 6;
    if (lane == 0) wsum[wv] = acc;
    __syncthreads();
    if (threadIdx.x == 0) atomicAdd(stats, wsum[0] + wsum[1] + wsum[2] + wsum[3]);
}

// ---------------------------------------------------------------------------
// CSR build (grouped by dst; self loops appended)
// ---------------------------------------------------------------------------
__global__ void csr_count(const int* __restrict__ ei, int* __restrict__ counts, int e, int n)
{
    int i = blockIdx.x * 256 + threadIdx.x;
    if (i >= e + n) return;
    int d = (i < e) ? ei[e + i] : (i - e);
    atomicAdd(&counts[d], 1);
}

__global__ __launch_bounds__(256)
void scan_block(const int* __restrict__ in, int* __restrict__ out,
                int* __restrict__ sums, int n)
{
    __shared__ int buf[2][256];
    int t = threadIdx.x;
    int i = blockIdx.x * 256 + t;
    int v = (i < n) ? in[i] : 0;
    buf[0][t] = v;
    __syncthreads();
    int cur = 0;
    #pragma unroll
    for (int d = 1; d < 256; d <<= 1) {
        int val = buf[cur][t] + ((t >= d) ? buf[cur][t - d] : 0);
        buf[cur ^ 1][t] = val;
        cur ^= 1;
        __syncthreads();
    }
    if (i < n) out[i] = buf[cur][t] - v;   // exclusive
    if (t == 255 && sums) sums[blockIdx.x] = buf[cur][255];
}

__global__ void scan_add(int* __restrict__ offs, const int* __restrict__ carry, int n)
{
    int i = blockIdx.x * 256 + threadIdx.x;
    if (i < n) offs[i] += carry[blockIdx.x];
}

__global__ void csr_fill(const int* __restrict__ ei, const int* __restrict__ offs,
                         int* __restrict__ cursor, int* __restrict__ csr_src, int e, int n)
{
    int i = blockIdx.x * 256 + threadIdx.x;
    if (i >= e + n) return;
    int d, s;
    if (i < e) { s = ei[i]; d = ei[e + i]; }
    else       { s = d = i - e; }
    int pos = offs[d] + atomicAdd(&cursor[d], 1);
    csr_src[pos] = s;
}

// ---------------------------------------------------------------------------
// Fused residual + LayerNorm epilogue for full-width (128-col) GEMM blocks.
// Pass 1: v = acc + bias + x, partial row stats via 16-lane shfl -> sm LDS.
// Barrier. Pass 2: x = v (fp32), lnout = LN(v) (fp16).
// Barriers are OUTSIDE row guards (all threads always reach them).
// ---------------------------------------------------------------------------
static __device__ __forceinline__ void ep_resln(
    f32x4 (&acc)[2][4], float* sm, int row0,
    int wr, int wc, int quad, int l15,
    const float* __restrict__ bias, const float* __restrict__ g,
    const float* __restrict__ bb,
    float* __restrict__ x, unsigned short* __restrict__ lnout, int n)
{
    #pragma unroll
    for (int i = 0; i < 2; ++i) {
        #pragma unroll
        for (int rr = 0; rr < 4; ++rr) {
            int rl = wr * 32 + i * 16 + quad * 4 + rr;
            size_t gr = (size_t)row0 + rl;
            float ps = 0.f, pq = 0.f;
            #pragma unroll
            for (int j = 0; j < 4; ++j) {
                int gc = wc * 64 + j * 16 + l15;
                float xv = (gr < (size_t)n) ? x[gr * DMODEL + gc] : 0.f;
                float v = acc[i][j][rr] + bias[gc] + xv;
                acc[i][j][rr] = v;
                ps += v; pq += v * v;
            }
            ps += __shfl_xor(ps, 1); pq += __shfl_xor(pq, 1);
            ps += __shfl_xor(ps, 2); pq += __shfl_xor(pq, 2);
            ps += __shfl_xor(ps, 4); pq += __shfl_xor(pq, 4);
            ps += __shfl_xor(ps, 8); pq += __shfl_xor(pq, 8);
            if (l15 == 0) { sm[(rl * 2 + wc) * 2 + 0] = ps; sm[(rl * 2 + wc) * 2 + 1] = pq; }
        }
    }
    __syncthreads();
    #pragma unroll
    for (int i = 0; i < 2; ++i) {
        #pragma unroll
        for (int rr = 0; rr < 4; ++rr) {
            int rl = wr * 32 + i * 16 + quad * 4 + rr;
            size_t gr = (size_t)row0 + rl;
            if (gr >= (size_t)n) continue;
            float su = sm[(rl * 2 + 0) * 2 + 0] + sm[(rl * 2 + 1) * 2 + 0];
            float sq = sm[(rl * 2 + 0) * 2 + 1] + sm[(rl * 2 + 1) * 2 + 1];
            float mu   = su * (1.f / 128.f);
            float var  = sq * (1.f / 128.f) - mu * mu;
            float rstd = rsqrtf(var + 1e-5f);
            #pragma unroll
            for (int j = 0; j < 4; ++j) {
                int gc = wc * 64 + j * 16 + l15;
                float v = acc[i][j][rr];
                x[gr * DMODEL + gc] = v;
                lnout[gr * DMODEL + gc] = f2h((v - mu) * rstd * g[gc] + bb[gc]);
            }
        }
    }
}

// ---------------------------------------------------------------------------
// B-resident fp16 MFMA GEMM (verified round-5 core).
// MODE epilogues:
//   0: fused QKV -> fp16 [q | kv interleaved], sec = blockIdx.y
//   1: outf[r][c] += acc + bias[c]                      (FFN2 last layer)
//   2: outb = gelu(acc + bias)  fp16                    (FFN1)
//   3: outb = acc + bias + Rb + norm(deg)[r]*wdeg[c] + bdeg[c]  fp16 (pos enc)
//   5: x += acc + bias  AND  outb = LN(x)  (Wo+LN2, FFN2+next-LN1)
// ---------------------------------------------------------------------------
template<int MODE, int KCH, int TPB>
__global__ __launch_bounds__(256)
void gemm_bres(const unsigned short* __restrict__ A, int strideA,
               const unsigned short* __restrict__ Bt, int strideB,
               const float* __restrict__ bias, const float* __restrict__ bias2,
               const float* __restrict__ bias3,
               const unsigned short* __restrict__ Rb,
               const float* __restrict__ deg, const float* __restrict__ stats, float mean,
               const float* __restrict__ wdeg, const float* __restrict__ bdeg,
               const float* __restrict__ lng, const float* __restrict__ lnb,
               float* __restrict__ outf, unsigned short* __restrict__ outb,
               int outStride, int n)
{
    __shared__ __align__(16) unsigned short As[64 * 130];
    __shared__ __align__(16) unsigned short Bs[128 * 130];
    __shared__ float sm[64 * 2 * 2];

    const int tid  = threadIdx.x;
    const int wave = tid >> 6, lane = tid & 63;
    const int wr = wave >> 1, wc = wave & 1;
    const int quad = lane >> 4, l15 = lane & 15;
    const int bc = blockIdx.y * 128;

    f32x4 acc[2][4] = {};
    short8 bfr[4][4];
    short8 pr[4];

    // prefetch A tile (ky=0, t=0)
    {
        const int row0 = blockIdx.x * TPB * 64;
        #pragma unroll
        for (int c = 0; c < 4; ++c) {
            int g = tid + c * 256;
            int r = g >> 4, col8 = g & 15;
            pr[c] = *(const short8*)(A + (size_t)(row0 + r) * strideA + col8 * 8);
        }
    }

    for (int ky = 0; ky < KCH; ++ky) {
        const int kOff = ky * 128;
        #pragma unroll
        for (int c = 0; c < 8; ++c) {
            int g = tid + c * 256;                 // 0..2047
            int r = g >> 4, col8 = g & 15;
            *(short8*)&Bs[r * 130 + col8 * 8] =
                *(const short8*)(Bt + (size_t)(bc + r) * strideB + kOff + col8 * 8);
        }
        for (int t = 0; t < TPB; ++t) {
            #pragma unroll
            for (int c = 0; c < 4; ++c) {
                int g = tid + c * 256;             // 0..1023
                int r = g >> 4, col8 = g & 15;
                *(short8*)&As[r * 130 + col8 * 8] = pr[c];
            }
            {
                int nt = t + 1, nky = ky;
                if (nt == TPB) { nt = 0; nky = ky + 1; }
                if (nky < KCH) {
                    const int nrow0 = (blockIdx.x * TPB + nt) * 64;
                    const int nkOff = nky * 128;
                    #pragma unroll
                    for (int c = 0; c < 4; ++c) {
                        int g = tid + c * 256;
                        int r = g >> 4, col8 = g & 15;
                        pr[c] = *(const short8*)(A + (size_t)(nrow0 + r) * strideA + nkOff + col8 * 8);
                    }
                }
            }
            __syncthreads();
            if (t == 0) {
                #pragma unroll
                for (int j = 0; j < 4; ++j)
                    #pragma unroll
                    for (int ks = 0; ks < 4; ++ks)
                        bfr[j][ks] = *(const short8*)&Bs[(wc * 64 + j * 16 + l15) * 130 + (ks * 4 + quad) * 8];
            }
            if (KCH == 1) {
                #pragma unroll
                for (int i = 0; i < 2; ++i)
                    #pragma unroll
                    for (int j = 0; j < 4; ++j)
                        acc[i][j] = f32x4{0.f, 0.f, 0.f, 0.f};
            }
            short8 af[2][4];
            #pragma unroll
            for (int i = 0; i < 2; ++i)
                #pragma unroll
                for (int ks = 0; ks < 4; ++ks)
                    af[i][ks] = *(const short8*)&As[(wr * 32 + i * 16 + l15) * 130 + (ks * 4 + quad) * 8];
            #pragma unroll
            for (int ks = 0; ks < 4; ++ks)
                #pragma unroll
                for (int i = 0; i < 2; ++i)
                    #pragma unroll
                    for (int j = 0; j < 4; ++j)
                        acc[i][j] = MFMAH(af[i][ks], bfr[j][ks], acc[i][j]);

            if (KCH == 1) {
                const int row0 = (blockIdx.x * TPB + t) * 64;
                if (MODE == 5) {
                    ep_resln(acc, sm, row0, wr, wc, quad, l15, bias, lng, lnb, outf, outb, n);
                } else {
                    float sdv = 0.f;
                    if (MODE == 3) sdv = sqrtf(stats[0] / (float)(n - 1)) + 1e-6f;
                    #pragma unroll
                    for (int i = 0; i < 2; ++i) {
                        #pragma unroll
                        for (int rr = 0; rr < 4; ++rr) {
                            size_t gr = (size_t)row0 + wr * 32 + i * 16 + quad * 4 + rr;
                            if (gr >= (size_t)n) continue;
                            #pragma unroll
                            for (int j = 0; j < 4; ++j) {
                                int col = wc * 64 + j * 16 + l15;
                                int gc  = bc + col;
                                float val = acc[i][j][rr];
                                if (MODE == 0) {
                                    int sec = blockIdx.y;
                                    const float* bp = (sec == 0) ? bias : (sec == 1 ? bias2 : bias3);
                                    val += bp[col];
                                    int idx = (sec == 0) ? col
                                            : (128 + ((col >> 1) << 2) + ((sec - 1) << 1) + (col & 1));
                                    outb[gr * (size_t)QKVW + idx] = f2h(val);
                                } else if (MODE == 1) {
                                    float* px = outf + gr * (size_t)outStride + gc;
                                    *px = *px + val + bias[gc];
                                } else if (MODE == 2) {
                                    val = gelu_fast(val + bias[gc]);
                                    outb[gr * (size_t)outStride + gc] = f2h(val);
                                } else if (MODE == 3) {
                                    float dg = (deg[gr] - mean) / sdv;
                                    val += bias[gc] + h2f(Rb[gr * (size_t)outStride + gc])
                                         + dg * wdeg[gc] + bdeg[gc];
                                    outb[gr * (size_t)outStride + gc] = f2h(val);
                                }
                            }
                        }
                    }
                }
            }
            __syncthreads();
        }
    }

    if (KCH > 1) {
        const int row0 = blockIdx.x * TPB * 64;
        if (MODE == 5) {
            ep_resln(acc, sm, row0, wr, wc, quad, l15, bias, lng, lnb, outf, outb, n);
        } else {
            #pragma unroll
            for (int i = 0; i < 2; ++i) {
                #pragma unroll
                for (int rr = 0; rr < 4; ++rr) {
                    size_t gr = (size_t)row0 + wr * 32 + i * 16 + quad * 4 + rr;
                    if (gr >= (size_t)n) continue;
                    #pragma unroll
                    for (int j = 0; j < 4; ++j) {
                        int col = wc * 64 + j * 16 + l15;
                        int gc  = bc + col;
                        if (MODE == 1) {
                            float* px = outf + gr * (size_t)outStride + gc;
                            *px = *px + acc[i][j][rr] + bias[gc];
                        }
                    }
                }
            }
        }
    }
}

// ---------------------------------------------------------------------------
// Attention: one wave per dst node, online softmax, 4-edge unroll with
// 4-deep prefetch. Lane l holds dims {2l,2l+1}; head = lane>>3.
// NaN check dropped: all inputs are finite fp16 (|q|,|k| <= 65504), so
// dot/shfl sums are finite; clamp to +-50 retained (matches reference).
// ---------------------------------------------------------------------------
__global__ __launch_bounds__(256)
void attn_kernel(const unsigned short* __restrict__ qkv,
                 const int* __restrict__ csr_src, const int* __restrict__ offs,
                 const int* __restrict__ counts,
                 unsigned short* __restrict__ aggr, int n)
{
    int wave = threadIdx.x >> 6;
    int lane = threadIdx.x & 63;
    int node = blockIdx.x * 4 + wave;
    if (node >= n) return;

    ushort2 qu = *(const ushort2*)(qkv + (size_t)node * QKVW + lane * 2);
    float qx = h2f(qu.x), qy = h2f(qu.y);
    int beg = offs[node], cnt = counts[node];

    const unsigned short* base = qkv + DMODEL + lane * 4;
    auto LKV = [&](int t) -> ushort4 {
        return *(const ushort4*)(base + (size_t)csr_src[beg + t] * QKVW);
    };

    float m = -1e30f, s = 0.f, ax = 0.f, ay = 0.f;
    ushort4 k0 = {0,0,0,0}, k1 = {0,0,0,0}, k2 = {0,0,0,0}, k3 = {0,0,0,0};
    k0 = LKV(0);                       // cnt >= 1 (self loop)
    if (cnt > 1) k1 = LKV(1);
    if (cnt > 2) k2 = LKV(2);
    if (cnt > 3) k3 = LKV(3);

    int t = 0;
    for (; t + 4 <= cnt; t += 4) {
        ushort4 c0 = k0, c1 = k1, c2 = k2, c3 = k3;
        int rem = cnt - t - 4;
        if (rem > 0) k0 = LKV(t + 4);
        if (rem > 1) k1 = LKV(t + 5);
        if (rem > 2) k2 = LKV(t + 6);
        if (rem > 3) k3 = LKV(t + 7);
        float p0 = qx * h2f(c0.x) + qy * h2f(c0.y);
        float p1 = qx * h2f(c1.x) + qy * h2f(c1.y);
        float p2 = qx * h2f(c2.x) + qy * h2f(c2.y);
        float p3 = qx * h2f(c3.x) + qy * h2f(c3.y);
        p0 += __shfl_xor(p0, 1); p1 += __shfl_xor(p1, 1); p2 += __shfl_xor(p2, 1); p3 += __shfl_xor(p3, 1);
        p0 += __shfl_xor(p0, 2); p1 += __shfl_xor(p1, 2); p2 += __shfl_xor(p2, 2); p3 += __shfl_xor(p3, 2);
        p0 += __shfl_xor(p0, 4); p1 += __shfl_xor(p1, 4); p2 += __shfl_xor(p2, 4); p3 += __shfl_xor(p3, 4);
        p0 = fminf(fmaxf(p0 * 0.25f, -50.f), 50.f);
        p1 = fminf(fmaxf(p1 * 0.25f, -50.f), 50.f);
        p2 = fminf(fmaxf(p2 * 0.25f, -50.f), 50.f);
        p3 = fminf(fmaxf(p3 * 0.25f, -50.f), 50.f);
        float nm = fmaxf(m, fmaxf(fmaxf(p0, p1), fmaxf(p2, p3)));
        float sc = __expf(m - nm);
        float e0 = __expf(p0 - nm), e1 = __expf(p1 - nm);
        float e2 = __expf(p2 - nm), e3 = __expf(p3 - nm);
        s  = s  * sc + ((e0 + e1) + (e2 + e3));
        ax = ax * sc + e0 * h2f(c0.z) + e1 * h2f(c1.z) + e2 * h2f(c2.z) + e3 * h2f(c3.z);
        ay = ay * sc + e0 * h2f(c0.w) + e1 * h2f(c1.w) + e2 * h2f(c2.w) + e3 * h2f(c3.w);
        m = nm;
    }
    int r = cnt - t;                    // 0..3 remaining, in k0..k2
    #define ONE_EDGE(kc) do { \
        float p = qx * h2f(kc.x) + qy * h2f(kc.y); \
        p += __shfl_xor(p, 1); p += __shfl_xor(p, 2); p += __shfl_xor(p, 4); \
        p = fminf(fmaxf(p * 0.25f, -50.f), 50.f); \
        float nm = fmaxf(m, p); \
        float sc = __expf(m - nm), e = __expf(p - nm); \
        s = s * sc + e; ax = ax * sc + e * h2f(kc.z); ay = ay * sc + e * h2f(kc.w); \
        m = nm; } while (0)
    if (r > 0) ONE_EDGE(k0);
    if (r > 1) ONE_EDGE(k1);
    if (r > 2) ONE_EDGE(k2);
    #undef ONE_EDGE

    float rcp = 1.0f / (s + 1e-16f);
    ushort2 o;
    o.x = f2h(ax * rcp);
    o.y = f2h(ay * rcp);
    *(ushort2*)(aggr + (size_t)node * DMODEL + lane * 2) = o;
}

// ---------------------------------------------------------------------------
extern "C" void kernel_launch(void* const* d_in, const int* in_sizes, int n_in,
                              void* d_out, int out_size, void* d_ws, size_t ws_size,
                              hipStream_t stream)
{
    const float* x_in  = (const float*)d_in[0];
    const int*   ei    = (const int*)d_in[1];
    const float* Wq    = (const float*)d_in[2];
    const float* Wk    = (const float*)d_in[3];
    const float* Wv    = (const float*)d_in[4];
    const float* Wo    = (const float*)d_in[5];
    const float* Wpos  = (const float*)d_in[6];
    const float* Wdeg  = (const float*)d_in[7];
    const float* W1    = (const float*)d_in[8];
    const float* W2    = (const float*)d_in[9];
    const float* bq    = (const float*)d_in[10];
    const float* bk    = (const float*)d_in[11];
    const float* bv    = (const float*)d_in[12];
    const float* bo    = (const float*)d_in[13];
    const float* bpos  = (const float*)d_in[14];
    const float* bdeg  = (const float*)d_in[15];
    const float* ln1_b = (const float*)d_in[16];
    const float* ln2_b = (const float*)d_in[17];
    const float* b1    = (const float*)d_in[18];
    const float* b2    = (const float*)d_in[19];
    const float* ln1_g = (const float*)d_in[20];
    const float* ln2_g = (const float*)d_in[21];

    const int n   = in_sizes[0] / DMODEL;   // 50000
    const int e   = in_sizes[1] / 2;        // 500000
    const int tot = e + n;

    float* x = (float*)d_out;               // running node features (fp32)

    // ---- workspace layout (256B-aligned slices) ----
    char* p = (char*)d_ws;
    auto alloc = [&](size_t bytes) -> void* {
        void* r = (void*)p;
        p += (bytes + 255) & ~(size_t)255;
        return r;
    };
    float* deg     = (float*)alloc((size_t)n * 4);
    float* stats   = (float*)alloc(256);
    int*   counts  = (int*)alloc((size_t)n * 4);
    int*   offs    = (int*)alloc((size_t)n * 4);
    int*   cursor  = (int*)alloc((size_t)n * 4);
    int*   bsums   = (int*)alloc(1024);
    int*   carry   = (int*)alloc(1024);
    int*   csr_src = (int*)alloc((size_t)tot * 4);
    unsigned short* xnb  = (unsigned short*)alloc((size_t)MPAD * DMODEL * 2);
    unsigned short* xp   = (unsigned short*)alloc((size_t)MPAD * DMODEL * 2);
    unsigned short* aggr = (unsigned short*)alloc((size_t)MPAD * DMODEL * 2);
    unsigned short* qkv  = (unsigned short*)alloc((size_t)MPAD * QKVW * 2);   // fp16
    unsigned short* hb   = (unsigned short*)alloc((size_t)MPAD * FFDIM * 2);
    unsigned short* wqkvt = (unsigned short*)alloc((size_t)NLAYER * QKVW * DMODEL * 2);
    unsigned short* wot  = (unsigned short*)alloc((size_t)NLAYER * DMODEL * DMODEL * 2);
    unsigned short* wpt  = (unsigned short*)alloc((size_t)NLAYER * DMODEL * DMODEL * 2);
    unsigned short* w1t  = (unsigned short*)alloc((size_t)NLAYER * DMODEL * FFDIM * 2);
    unsigned short* w2t  = (unsigned short*)alloc((size_t)NLAYER * FFDIM * DMODEL * 2);

    const int nb_n = (n + 255) / 256;
    const int nb_e = (e + 255) / 256;
    const int nb_t = (tot + 255) / 256;
    const int nscan = nb_n;

    hipMemcpyAsync(x, x_in, (size_t)n * DMODEL * 4, hipMemcpyDeviceToDevice, stream);

    // setup: 1 wconv launch + 1 init launch
    {
        const int totalW = 5 * NLAYER * DMODEL * DMODEL + 2 * NLAYER * DMODEL * FFDIM;
        wconv_all<<<(totalW + 255) / 256, 256, 0, stream>>>(Wq, Wk, Wv, Wo, Wpos, W1, W2,
                                                            wqkvt, wot, wpt, w1t, w2t);
    }
    init_all<<<nb_n, 256, 0, stream>>>(deg, counts, cursor, stats, n);

    const float mean = (float)((double)tot / (double)n);
    deg_count<<<nb_e, 256, 0, stream>>>(ei, deg, e);
    deg_var<<<196, 256, 0, stream>>>(deg, stats, mean, n);

    csr_count<<<nb_t, 256, 0, stream>>>(ei, counts, e, n);
    scan_block<<<nscan, 256, 0, stream>>>(counts, offs, bsums, n);
    scan_block<<<1, 256, 0, stream>>>(bsums, carry, nullptr, nscan);
    scan_add<<<nscan, 256, 0, stream>>>(offs, carry, n);
    csr_fill<<<nb_t, 256, 0, stream>>>(ei, offs, cursor, csr_src, e, n);

    const int nTiles  = MPAD / 64;           // 782
    const int gx2     = nTiles / 2;          // 391 (TPB=2)
    const int ln_grid = (n + 3) / 4;

    // layer-0 LN1 (the only standalone LN; later LNs are fused into epilogues)
    ln_kernel<<<ln_grid, 256, 0, stream>>>(x, ln1_g, ln1_b, xnb, n);

    for (int l = 0; l < NLAYER; ++l) {
        const size_t DD = (size_t)DMODEL * DMODEL;
        const float* wdeg = Wdeg + (size_t)l * DMODEL;
        const unsigned short* wqkv = wqkvt + (size_t)l * QKVW * DMODEL;
        const unsigned short* wo   = wot + l * DD;
        const unsigned short* wpos = wpt + l * DD;
        const unsigned short* w1   = w1t + (size_t)l * DMODEL * FFDIM;
        const unsigned short* w2   = w2t + (size_t)l * FFDIM * DMODEL;

        // xp = xn + xn@Wpos + bpos + norm(deg)*wdeg + bdeg   (fp16 out)
        gemm_bres<3, 1, 2><<<dim3(gx2, 1), 256, 0, stream>>>(
            xnb, DMODEL, wpos, DMODEL,
            bpos + l * DMODEL, nullptr, nullptr,
            xnb, deg, stats, mean, wdeg, bdeg + l * DMODEL,
            nullptr, nullptr,
            nullptr, xp, DMODEL, n);
        // fused QKV -> fp16 qkv buffer (q | interleaved kv)
        gemm_bres<0, 1, 2><<<dim3(gx2, 3), 256, 0, stream>>>(
            xp, DMODEL, wqkv, DMODEL,
            bq + l * DMODEL, bk + l * DMODEL, bv + l * DMODEL,
            nullptr, nullptr, nullptr, 0.f, nullptr, nullptr,
            nullptr, nullptr,
            nullptr, qkv, QKVW, n);
        // attention -> aggr (fp16)
        attn_kernel<<<ln_grid, 256, 0, stream>>>(qkv, csr_src, offs, counts, aggr, n);
        // x += aggr@Wo + bo  AND  xnb = LN2(x)   (fused)
        gemm_bres<5, 1, 2><<<dim3(gx2, 1), 256, 0, stream>>>(
            aggr, DMODEL, wo, DMODEL,
            bo + l * DMODEL, nullptr, nullptr,
            nullptr, nullptr, nullptr, 0.f, nullptr, nullptr,
            ln2_g + l * DMODEL, ln2_b + l * DMODEL,
            x, xnb, DMODEL, n);
        // hb = gelu(xnb @ W1 + b1)
        gemm_bres<2, 1, 2><<<dim3(gx2, 4), 256, 0, stream>>>(
            xnb, DMODEL, w1, DMODEL,
            b1 + l * FFDIM, nullptr, nullptr,
            nullptr, nullptr, nullptr, 0.f, nullptr, nullptr,
            nullptr, nullptr,
            nullptr, hb, FFDIM, n);
        // x += hb @ W2 + b2; on layer 0 also emit xnb = LN1_{l+1}(x)
        if (l + 1 < NLAYER) {
            gemm_bres<5, 4, 1><<<dim3(nTiles, 1), 256, 0, stream>>>(
                hb, FFDIM, w2, FFDIM,
                b2 + l * DMODEL, nullptr, nullptr,
                nullptr, nullptr, nullptr, 0.f, nullptr, nullptr,
                ln1_g + (l + 1) * DMODEL, ln1_b + (l + 1) * DMODEL,
                x, xnb, DMODEL, n);
        } else {
            gemm_bres<1, 4, 1><<<dim3(nTiles, 1), 256, 0, stream>>>(
                hb, FFDIM, w2, FFDIM,
                b2 + l * DMODEL, nullptr, nullptr,
                nullptr, nullptr, nullptr, 0.f, nullptr, nullptr,
                nullptr, nullptr,
                x, nullptr, DMODEL, n);
        }
    }
}